// Round 1
// baseline (11301.729 us; speedup 1.0000x reference)
//
#include <hip/hip_runtime.h>

// LSTM stack: B=64, T=256, N=M=1024, L=2.
// Persistent cooperative kernel: 256 WGs (1/CU), 512 threads (8 waves).
// Waves 0-3: layer0 (btiles 0-3), waves 4-7: layer1 (btiles 0-3).
// Pipelined: iteration k computes layer0@t=k and layer1@t=k-1 -> 1 grid barrier/iter.
// Weights bf16, fragment-packed in 128KB LDS. h broadcast via bf16 L2 buffers.
// ws layout: [0..128) barrier, [4096..) h0buf (2x64x1024 bf16), then h1buf, then x_bf16.

#define T_STEPS 256
#define B_SZ 64
#define M_SZ 1024
#define N_SZ 1024
#define G4M 4096
#define BM 65536                       // B*M
#define OUTS ((size_t)16777216)        // B*T*M

typedef short short8 __attribute__((ext_vector_type(8)));
typedef float f32x4 __attribute__((ext_vector_type(4)));

static __device__ __forceinline__ unsigned short f2bf(float f) {
  union { float f; unsigned int u; } v; v.f = f;
  unsigned int u = v.u;
  unsigned int r = (u + 0x7FFFu + ((u >> 16) & 1u)) >> 16;
  return (unsigned short)r;
}

static __device__ __forceinline__ float sigf(float x) {
  return 1.f / (1.f + __expf(-x));
}
static __device__ __forceinline__ float tanhfast(float x) {
  return 2.f / (1.f + __expf(-2.f * x)) - 1.f;
}

__global__ void convert_x_kernel(const float* __restrict__ x,
                                 unsigned short* __restrict__ xb, int n4) {
  int i = blockIdx.x * blockDim.x + threadIdx.x;
  int stride = gridDim.x * blockDim.x;
  for (; i < n4; i += stride) {
    float4 v = reinterpret_cast<const float4*>(x)[i];
    ushort4 o;
    o.x = f2bf(v.x); o.y = f2bf(v.y); o.z = f2bf(v.z); o.w = f2bf(v.w);
    reinterpret_cast<ushort4*>(xb)[i] = o;
  }
}

__global__ void init_h_kernel(const float* __restrict__ h,
                              unsigned short* __restrict__ h0b,
                              unsigned short* __restrict__ h1b) {
  int i = blockIdx.x * blockDim.x + threadIdx.x;  // 0..65535
  // layer0 init read at iter 0 from parity 1; layer1 init read at iter 1 from parity 0
  h0b[BM + i] = f2bf(h[i]);
  h1b[i]      = f2bf(h[BM + i]);
}

__device__ __forceinline__ void grid_barrier(int* cnt, int* gen, int target) {
  __syncthreads();
  if (threadIdx.x == 0) {
    __threadfence();  // device-scope release of this WG's writes
    int prev = __hip_atomic_fetch_add(cnt, 1, __ATOMIC_ACQ_REL, __HIP_MEMORY_SCOPE_AGENT);
    if (prev == (int)gridDim.x - 1) {
      __hip_atomic_store(cnt, 0, __ATOMIC_RELAXED, __HIP_MEMORY_SCOPE_AGENT);
      __hip_atomic_fetch_add(gen, 1, __ATOMIC_RELEASE, __HIP_MEMORY_SCOPE_AGENT);
    } else {
      int guard = 0;
      while (__hip_atomic_load(gen, __ATOMIC_ACQUIRE, __HIP_MEMORY_SCOPE_AGENT) < target) {
        __builtin_amdgcn_s_sleep(2);
        if (++guard > (1 << 19)) break;  // failsafe: wrong answer instead of hang
      }
    }
  }
  __syncthreads();
}

__global__ __launch_bounds__(512, 1) void lstm_persistent(
    const unsigned short* __restrict__ xb,   // [B][T][N] bf16
    const float* __restrict__ c_in,          // [L][B][M]
    const float* __restrict__ Wx,            // [L][4M][N]
    const float* __restrict__ Wh,            // [L][4M][M]
    const float* __restrict__ bias,          // [L][4M]
    float* __restrict__ out,                 // outs | h_last | c_last
    unsigned short* __restrict__ h0b,        // [2][B][M] bf16
    unsigned short* __restrict__ h1b,        // [2][B][M] bf16
    int* cnt, int* gen) {
  // Fragment-packed weights: sW[mat][ktile][lane] holds 8 bf16 along K.
  __shared__ short8 sW[4][32][64];  // 128 KiB

  const int cu = blockIdx.x;
  const int tid = threadIdx.x;
  const int lane = tid & 63;
  const int wave = tid >> 6;
  const int layer = wave >> 2;   // 0..1
  const int btile = wave & 3;    // 0..3
  const int q = lane >> 4;       // gate group / k-subgroup
  const int bl = lane & 15;
  const int bg = btile * 16 + bl;  // global batch row
  const int m0 = cu * 4;           // this CU's hidden units: m0..m0+3

  // ---- stage weights (once) ----
  const float* gbase[4] = { Wx, Wh, Wx + (size_t)G4M * N_SZ, Wh + (size_t)G4M * M_SZ };
  for (int mat = 0; mat < 4; ++mat) {
    const float* base = gbase[mat];
    for (int s = tid; s < 32 * 64; s += 512) {
      int kt = s >> 6, ls = s & 63;
      int r = ls & 15;                       // fragment row = gate row index
      int k0 = kt * 32 + (ls >> 4) * 8;      // k offset of this lane's 8 elems
      int j = (r >> 2) * 1024 + m0 + (r & 3);  // global gate row: q*1024 + m
      const float* src = base + (size_t)j * 1024 + k0;
      float4 a = reinterpret_cast<const float4*>(src)[0];
      float4 b2 = reinterpret_cast<const float4*>(src)[1];
      short8 w;
      w[0] = (short)f2bf(a.x); w[1] = (short)f2bf(a.y);
      w[2] = (short)f2bf(a.z); w[3] = (short)f2bf(a.w);
      w[4] = (short)f2bf(b2.x); w[5] = (short)f2bf(b2.y);
      w[6] = (short)f2bf(b2.z); w[7] = (short)f2bf(b2.w);
      sW[mat][kt][ls] = w;
    }
  }
  __syncthreads();

  // ---- per-lane state ----
  float c_st[4];
#pragma unroll
  for (int e = 0; e < 4; ++e)
    c_st[e] = c_in[layer * BM + bg * M_SZ + m0 + e];  // replicated across q-groups

  float bs[4];
#pragma unroll
  for (int e = 0; e < 4; ++e)
    bs[e] = bias[layer * G4M + q * 1024 + m0 + e];  // bias for acc row r=q*4+e

  const int matA = (layer == 0) ? 0 : 2;
  const int matR = (layer == 0) ? 1 : 3;
  const int ko = q * 8;

  for (int k = 0; k <= T_STEPS; ++k) {
    const int t = (layer == 0) ? k : (k - 1);
    const bool active = (layer == 0) ? (k < T_STEPS) : (k >= 1);
    if (active) {
      const int pr = (k + 1) & 1;  // read parity (state from iter k-1)
      const int pw = k & 1;        // write parity
      const unsigned short* inA =
          (layer == 0) ? (xb + ((size_t)bg * T_STEPS + t) * N_SZ)
                       : (h0b + pr * BM + bg * M_SZ);
      const unsigned short* inR =
          (layer == 0) ? (h0b + pr * BM + bg * M_SZ)
                       : (h1b + pr * BM + bg * M_SZ);

      f32x4 accA = { bs[0], bs[1], bs[2], bs[3] };
      f32x4 accR = { 0.f, 0.f, 0.f, 0.f };
#pragma unroll 4
      for (int kt = 0; kt < 32; ++kt) {
        short8 fa = *reinterpret_cast<const short8*>(inA + kt * 32 + ko);
        short8 fr = *reinterpret_cast<const short8*>(inR + kt * 32 + ko);
        accA = __builtin_amdgcn_mfma_f32_16x16x32_bf16(sW[matA][kt][lane], fa, accA, 0, 0, 0);
        accR = __builtin_amdgcn_mfma_f32_16x16x32_bf16(sW[matR][kt][lane], fr, accR, 0, 0, 0);
      }

      // lane l holds D[r=(l>>4)*4+e][b=l&15]; gather i,f,g,o for (b=bl, m=m0+e)
      float hv[4];
#pragma unroll
      for (int e = 0; e < 4; ++e) {
        float ge_i = __shfl(accA[e] + accR[e], bl);
        float ge_f = __shfl(accA[e] + accR[e], bl + 16);
        float ge_g = __shfl(accA[e] + accR[e], bl + 32);
        float ge_o = __shfl(accA[e] + accR[e], bl + 48);
        float gi = sigf(ge_i);
        float gf = sigf(ge_f);
        float gg = tanhfast(ge_g);
        float go = sigf(ge_o);
        float c = gf * c_st[e] + gi * gg;
        c_st[e] = c;
        hv[e] = go * tanhfast(c);
      }

      if (q == 0) {
        unsigned short* hdst =
            ((layer == 0) ? h0b : h1b) + pw * BM + bg * M_SZ + m0;
        ushort4 hb;
        hb.x = f2bf(hv[0]); hb.y = f2bf(hv[1]);
        hb.z = f2bf(hv[2]); hb.w = f2bf(hv[3]);
        *reinterpret_cast<ushort4*>(hdst) = hb;
        if (layer == 1) {
          float4 ov = { hv[0], hv[1], hv[2], hv[3] };
          *reinterpret_cast<float4*>(out + ((size_t)bg * T_STEPS + t) * M_SZ + m0) = ov;
        }
        if (t == T_STEPS - 1) {
          float* hout = out + OUTS + (size_t)layer * BM + (size_t)bg * M_SZ + m0;
          float* cout = out + OUTS + 2 * (size_t)BM + (size_t)layer * BM + (size_t)bg * M_SZ + m0;
#pragma unroll
          for (int e = 0; e < 4; ++e) { hout[e] = hv[e]; cout[e] = c_st[e]; }
        }
      }
    }
    if (k < T_STEPS) grid_barrier(cnt, gen, k + 1);
  }
}

extern "C" void kernel_launch(void* const* d_in, const int* in_sizes, int n_in,
                              void* d_out, int out_size, void* d_ws, size_t ws_size,
                              hipStream_t stream) {
  (void)in_sizes; (void)n_in; (void)out_size; (void)ws_size;
  const float* x  = (const float*)d_in[0];
  const float* h  = (const float*)d_in[1];
  const float* c  = (const float*)d_in[2];
  const float* Wx = (const float*)d_in[3];
  const float* Wh = (const float*)d_in[4];
  const float* b  = (const float*)d_in[5];
  float* out = (float*)d_out;

  char* ws = (char*)d_ws;
  int* cnt = (int*)ws;            // barrier counter
  int* gen = (int*)(ws + 64);     // barrier generation
  unsigned short* h0b = (unsigned short*)(ws + 4096);
  unsigned short* h1b = (unsigned short*)(ws + 4096 + 2 * BM * sizeof(unsigned short));
  unsigned short* xb  = (unsigned short*)(ws + 4096 + 4 * BM * sizeof(unsigned short));
  // total ws use: 4096 + 512KB + 32MB  (~34 MB)

  hipMemsetAsync(ws, 0, 128, stream);
  convert_x_kernel<<<2048, 256, 0, stream>>>(x, xb, (B_SZ * T_STEPS * N_SZ) / 4);
  init_h_kernel<<<256, 256, 0, stream>>>(h, h0b, h1b);
  lstm_persistent<<<256, 512, 0, stream>>>(xb, c, Wx, Wh, b, out, h0b, h1b, cnt, gen);
}

// Round 2
// 7413.599 us; speedup vs baseline: 1.5245x; 1.5245x over previous
//
#include <hip/hip_runtime.h>

// LSTM stack: B=64, T=256, N=M=1024, L=2.
// Persistent cooperative kernel: 256 WGs (1/CU), 1024 threads (16 waves).
// Waves 0-7: (layer, btile) compute kt 0..15; waves 8-15: same (layer,btile), kt 16..31.
// Partial accs reduced via LDS. 1 relaxed tree grid-barrier per step.
// Weights bf16 fragment-packed in 128KB LDS. h via write-through/coherent-bypass
// relaxed agent atomics (no L2 invalidate => x stays cacheable).

#define T_STEPS 256
#define B_SZ 64
#define M_SZ 1024
#define N_SZ 1024
#define G4M 4096
#define BM 65536                       // B*M
#define OUTS ((size_t)16777216)        // B*T*M

typedef short short8 __attribute__((ext_vector_type(8)));
typedef float f32x4 __attribute__((ext_vector_type(4)));

static __device__ __forceinline__ unsigned short f2bf(float f) {
  union { float f; unsigned int u; } v; v.f = f;
  unsigned int u = v.u;
  unsigned int r = (u + 0x7FFFu + ((u >> 16) & 1u)) >> 16;
  return (unsigned short)r;
}

static __device__ __forceinline__ float sigf(float x) {
  return 1.f / (1.f + __expf(-x));
}
static __device__ __forceinline__ float tanhfast(float x) {
  return 2.f / (1.f + __expf(-2.f * x)) - 1.f;
}

// 16 bf16 = two 8B coherent (L1/L2-bypassing) relaxed agent loads
static __device__ __forceinline__ short8 load_h8(const unsigned short* p) {
  union { unsigned long long u[2]; short8 s; } cv;
  cv.u[0] = __hip_atomic_load((const unsigned long long*)p, __ATOMIC_RELAXED,
                              __HIP_MEMORY_SCOPE_AGENT);
  cv.u[1] = __hip_atomic_load((const unsigned long long*)(p + 4), __ATOMIC_RELAXED,
                              __HIP_MEMORY_SCOPE_AGENT);
  return cv.s;
}

__global__ void convert_x_kernel(const float* __restrict__ x,
                                 unsigned short* __restrict__ xb, int n4) {
  int i = blockIdx.x * blockDim.x + threadIdx.x;
  int stride = gridDim.x * blockDim.x;
  for (; i < n4; i += stride) {
    float4 v = reinterpret_cast<const float4*>(x)[i];
    ushort4 o;
    o.x = f2bf(v.x); o.y = f2bf(v.y); o.z = f2bf(v.z); o.w = f2bf(v.w);
    reinterpret_cast<ushort4*>(xb)[i] = o;
  }
}

__global__ void init_h_kernel(const float* __restrict__ h,
                              unsigned short* __restrict__ h0b,
                              unsigned short* __restrict__ h1b) {
  int i = blockIdx.x * blockDim.x + threadIdx.x;  // 0..65535
  h0b[BM + i] = f2bf(h[i]);      // layer0 reads parity 1 at iter 0
  h1b[i]      = f2bf(h[BM + i]); // layer1 reads parity 0 at iter 1
}

// Monotonic relaxed tree barrier: 8 leaves (64B apart) -> root -> gen.
// __syncthreads() drains vmcnt for every thread (HIP semantics), and h stores
// are write-through agent atomics, so arrival implies h visible. No fences.
__device__ __forceinline__ void grid_barrier(int* bar, int cu, int target) {
  __syncthreads();
  if (threadIdx.x == 0) {
    int* leaf = bar + 16 * (cu & 7);
    int* root = bar + 16 * 8;
    int* gen  = bar + 16 * 9;
    int prev = __hip_atomic_fetch_add(leaf, 1, __ATOMIC_RELAXED, __HIP_MEMORY_SCOPE_AGENT);
    if ((prev & 31) == 31) {                       // 32 WGs per leaf
      int pr = __hip_atomic_fetch_add(root, 1, __ATOMIC_RELAXED, __HIP_MEMORY_SCOPE_AGENT);
      if ((pr & 7) == 7) {
        __hip_atomic_fetch_add(gen, 1, __ATOMIC_RELAXED, __HIP_MEMORY_SCOPE_AGENT);
      }
    }
    int guard = 0;
    while (__hip_atomic_load(gen, __ATOMIC_RELAXED, __HIP_MEMORY_SCOPE_AGENT) < target) {
      __builtin_amdgcn_s_sleep(1);
      if (++guard > (1 << 20)) break;  // failsafe: wrong answer instead of hang
    }
  }
  __syncthreads();
}

__global__ __launch_bounds__(1024, 4) void lstm_persistent(
    const unsigned short* __restrict__ xb,   // [B][T][N] bf16 (cached reads)
    const float* __restrict__ c_in,          // [L][B][M]
    const float* __restrict__ Wx,            // [L][4M][N]
    const float* __restrict__ Wh,            // [L][4M][M]
    const float* __restrict__ bias,          // [L][4M]
    float* __restrict__ out,                 // outs | h_last | c_last
    unsigned short* __restrict__ h0b,        // [2][B][M] bf16 (coherent)
    unsigned short* __restrict__ h1b,        // [2][B][M] bf16 (coherent)
    int* bar) {
  __shared__ short8 sW[4][32][64];  // 128 KiB fragment-packed weights
  __shared__ f32x4 red[8][64];      // 8 KiB partial-acc reduce buffer

  const int cu = blockIdx.x;
  const int tid = threadIdx.x;
  const int lane = tid & 63;
  const int wave = tid >> 6;     // 0..15
  const int khalf = wave >> 3;   // 0: kt 0..15, 1: kt 16..31
  const int wl = wave & 7;
  const int layer = wl >> 2;     // 0..1
  const int btile = wl & 3;      // 0..3
  const int q = lane >> 4;
  const int bl = lane & 15;
  const int bg = btile * 16 + bl;
  const int m0 = cu * 4;

  // ---- stage weights (once) ----
  const float* gbase[4] = { Wx, Wh, Wx + (size_t)G4M * N_SZ, Wh + (size_t)G4M * M_SZ };
  for (int mat = 0; mat < 4; ++mat) {
    const float* base = gbase[mat];
    for (int s = tid; s < 32 * 64; s += 1024) {
      int kt = s >> 6, ls = s & 63;
      int r = ls & 15;
      int k0 = kt * 32 + (ls >> 4) * 8;
      int j = (r >> 2) * 1024 + m0 + (r & 3);
      const float* src = base + (size_t)j * 1024 + k0;
      float4 a = reinterpret_cast<const float4*>(src)[0];
      float4 b2 = reinterpret_cast<const float4*>(src)[1];
      short8 w;
      w[0] = (short)f2bf(a.x); w[1] = (short)f2bf(a.y);
      w[2] = (short)f2bf(a.z); w[3] = (short)f2bf(a.w);
      w[4] = (short)f2bf(b2.x); w[5] = (short)f2bf(b2.y);
      w[6] = (short)f2bf(b2.z); w[7] = (short)f2bf(b2.w);
      sW[mat][kt][ls] = w;
    }
  }
  __syncthreads();

  // ---- per-lane state (low waves own c-state, bias, pointwise) ----
  float c_st[4] = {0.f, 0.f, 0.f, 0.f};
  float bs[4] = {0.f, 0.f, 0.f, 0.f};
  if (khalf == 0) {
#pragma unroll
    for (int e = 0; e < 4; ++e) {
      c_st[e] = c_in[layer * BM + bg * M_SZ + m0 + e];
      bs[e] = bias[layer * G4M + q * 1024 + m0 + e];
    }
  }

  const int ko = q * 8;
  const int ktb = khalf * 16;

  for (int k = 0; k <= T_STEPS; ++k) {
    const int t = layer ? (k - 1) : k;
    const bool active = layer ? (k >= 1) : (k < T_STEPS);
    f32x4 accA = { 0.f, 0.f, 0.f, 0.f };
    f32x4 accR = { 0.f, 0.f, 0.f, 0.f };
    if (active) {
      const int pr = (k + 1) & 1;  // read parity (state from iter k-1)
      if (khalf == 0) { accA[0] = bs[0]; accA[1] = bs[1]; accA[2] = bs[2]; accA[3] = bs[3]; }
      if (layer == 0) {
        const unsigned short* inA = xb + ((size_t)bg * T_STEPS + t) * N_SZ;
        const unsigned short* inR = h0b + pr * BM + bg * M_SZ;
#pragma unroll 8
        for (int kk = 0; kk < 16; ++kk) {
          int kt = ktb + kk;
          short8 fa = *reinterpret_cast<const short8*>(inA + kt * 32 + ko);
          short8 fr = load_h8(inR + kt * 32 + ko);
          accA = __builtin_amdgcn_mfma_f32_16x16x32_bf16(sW[0][kt][lane], fa, accA, 0, 0, 0);
          accR = __builtin_amdgcn_mfma_f32_16x16x32_bf16(sW[1][kt][lane], fr, accR, 0, 0, 0);
        }
      } else {
        const unsigned short* inA = h0b + pr * BM + bg * M_SZ;
        const unsigned short* inR = h1b + pr * BM + bg * M_SZ;
#pragma unroll 8
        for (int kk = 0; kk < 16; ++kk) {
          int kt = ktb + kk;
          short8 fa = load_h8(inA + kt * 32 + ko);
          short8 fr = load_h8(inR + kt * 32 + ko);
          accA = __builtin_amdgcn_mfma_f32_16x16x32_bf16(sW[2][kt][lane], fa, accA, 0, 0, 0);
          accR = __builtin_amdgcn_mfma_f32_16x16x32_bf16(sW[3][kt][lane], fr, accR, 0, 0, 0);
        }
      }
      if (khalf == 1) red[wl][lane] = accA + accR;
    }
    __syncthreads();
    if (active && khalf == 0) {
      f32x4 tot = accA + accR + red[wl][lane];
      float hv[4];
#pragma unroll
      for (int e = 0; e < 4; ++e) {
        float ge_i = __shfl(tot[e], bl);
        float ge_f = __shfl(tot[e], bl + 16);
        float ge_g = __shfl(tot[e], bl + 32);
        float ge_o = __shfl(tot[e], bl + 48);
        float gi = sigf(ge_i);
        float gf = sigf(ge_f);
        float gg = tanhfast(ge_g);
        float go = sigf(ge_o);
        float c = gf * c_st[e] + gi * gg;
        c_st[e] = c;
        hv[e] = go * tanhfast(c);
      }
      if (q == 0) {
        const int pw = k & 1;
        unsigned short* hdst = ((layer == 0) ? h0b : h1b) + pw * BM + bg * M_SZ + m0;
        unsigned long long hb =
            (unsigned long long)f2bf(hv[0]) |
            ((unsigned long long)f2bf(hv[1]) << 16) |
            ((unsigned long long)f2bf(hv[2]) << 32) |
            ((unsigned long long)f2bf(hv[3]) << 48);
        // write-through agent store: visible without wbl2 once vmcnt drains
        __hip_atomic_store((unsigned long long*)hdst, hb, __ATOMIC_RELAXED,
                           __HIP_MEMORY_SCOPE_AGENT);
        if (layer == 1) {
          float4 ov = { hv[0], hv[1], hv[2], hv[3] };
          *reinterpret_cast<float4*>(out + ((size_t)bg * T_STEPS + t) * M_SZ + m0) = ov;
        }
        if (t == T_STEPS - 1) {
          float* hout = out + OUTS + (size_t)layer * BM + (size_t)bg * M_SZ + m0;
          float* cout = out + OUTS + 2 * (size_t)BM + (size_t)layer * BM + (size_t)bg * M_SZ + m0;
#pragma unroll
          for (int e = 0; e < 4; ++e) { hout[e] = hv[e]; cout[e] = c_st[e]; }
        }
      }
    }
    if (k < T_STEPS) grid_barrier(bar, cu, k + 1);
  }
}

extern "C" void kernel_launch(void* const* d_in, const int* in_sizes, int n_in,
                              void* d_out, int out_size, void* d_ws, size_t ws_size,
                              hipStream_t stream) {
  (void)in_sizes; (void)n_in; (void)out_size; (void)ws_size;
  const float* x  = (const float*)d_in[0];
  const float* h  = (const float*)d_in[1];
  const float* c  = (const float*)d_in[2];
  const float* Wx = (const float*)d_in[3];
  const float* Wh = (const float*)d_in[4];
  const float* b  = (const float*)d_in[5];
  float* out = (float*)d_out;

  char* ws = (char*)d_ws;
  int* bar = (int*)ws;                              // 10 cachelines of counters
  unsigned short* h0b = (unsigned short*)(ws + 4096);
  unsigned short* h1b = (unsigned short*)(ws + 4096 + 2 * BM * sizeof(unsigned short));
  unsigned short* xb  = (unsigned short*)(ws + 4096 + 4 * BM * sizeof(unsigned short));

  hipMemsetAsync(ws, 0, 1024, stream);
  convert_x_kernel<<<2048, 256, 0, stream>>>(x, xb, (B_SZ * T_STEPS * N_SZ) / 4);
  init_h_kernel<<<256, 256, 0, stream>>>(h, h0b, h1b);
  lstm_persistent<<<256, 1024, 0, stream>>>(xb, c, Wx, Wh, b, out, h0b, h1b, bar);
}

// Round 4
// 5270.346 us; speedup vs baseline: 2.1444x; 1.4067x over previous
//
#include <hip/hip_runtime.h>

// LSTM stack: B=64, T=256, N=M=1024, L=2.
// Persistent cooperative kernel: 256 WGs (1/CU), 1024 threads (16 waves).
// Waves 0-7: (layer, btile) kt 0..15; waves 8-15: same (layer,btile), kt 16..31.
// Partial accs reduced via LDS. 1 relaxed tree grid-barrier per step.
// Weights bf16 fragment-packed in 128KB LDS.
// Coherence scheme: h stores are write-through agent atomics (never dirty L2);
// out stores are write-through asm (sc0 sc1); h loads are NORMAL cached loads;
// after each grid barrier thread0 issues buffer_inv sc0 sc1 to drop stale
// clean L1/L2 lines so h refills fresh from the coherent LLC.

#define T_STEPS 256
#define B_SZ 64
#define M_SZ 1024
#define N_SZ 1024
#define G4M 4096
#define BM 65536                       // B*M
#define OUTS ((size_t)16777216)        // B*T*M

typedef short short8 __attribute__((ext_vector_type(8)));
typedef float f32x4 __attribute__((ext_vector_type(4)));

static __device__ __forceinline__ unsigned short f2bf(float f) {
  union { float f; unsigned int u; } v; v.f = f;
  unsigned int u = v.u;
  unsigned int r = (u + 0x7FFFu + ((u >> 16) & 1u)) >> 16;
  return (unsigned short)r;
}

static __device__ __forceinline__ float sigf(float x) {
  return 1.f / (1.f + __expf(-x));
}
static __device__ __forceinline__ float tanhfast(float x) {
  return 2.f / (1.f + __expf(-2.f * x)) - 1.f;
}

// write-through 16B store: goes to LLC, never dirties L2 (inv-safe)
static __device__ __forceinline__ void store_wt16(void* p, f32x4 v) {
  asm volatile("global_store_dwordx4 %0, %1, off sc0 sc1" :: "v"(p), "v"(v) : "memory");
}

__global__ void convert_x_kernel(const float* __restrict__ x,
                                 unsigned short* __restrict__ xb, int n4) {
  int i = blockIdx.x * blockDim.x + threadIdx.x;
  int stride = gridDim.x * blockDim.x;
  for (; i < n4; i += stride) {
    float4 v = reinterpret_cast<const float4*>(x)[i];
    ushort4 o;
    o.x = f2bf(v.x); o.y = f2bf(v.y); o.z = f2bf(v.z); o.w = f2bf(v.w);
    reinterpret_cast<ushort4*>(xb)[i] = o;
  }
}

__global__ void init_h_kernel(const float* __restrict__ h,
                              unsigned short* __restrict__ h0b,
                              unsigned short* __restrict__ h1b) {
  int i = blockIdx.x * blockDim.x + threadIdx.x;  // 0..65535
  h0b[BM + i] = f2bf(h[i]);      // layer0 reads parity 1 at iter 0
  h1b[i]      = f2bf(h[BM + i]); // layer1 reads parity 0 at iter 1
}

// Monotonic relaxed tree barrier: 8 leaves (64B apart) -> root -> gen.
// Producers' write-through stores drain (vmcnt) before s_barrier => visible at
// LLC by arrival. After release, drop stale clean L1/L2 lines with buffer_inv.
__device__ __forceinline__ void grid_barrier(int* bar, int cu, int target) {
  __syncthreads();
  if (threadIdx.x == 0) {
    int* leaf = bar + 16 * (cu & 7);
    int* root = bar + 16 * 8;
    int* gen  = bar + 16 * 9;
    int prev = __hip_atomic_fetch_add(leaf, 1, __ATOMIC_RELAXED, __HIP_MEMORY_SCOPE_AGENT);
    if ((prev & 31) == 31) {                       // 32 WGs per leaf
      int pr = __hip_atomic_fetch_add(root, 1, __ATOMIC_RELAXED, __HIP_MEMORY_SCOPE_AGENT);
      if ((pr & 7) == 7) {
        __hip_atomic_fetch_add(gen, 1, __ATOMIC_RELAXED, __HIP_MEMORY_SCOPE_AGENT);
      }
    }
    int guard = 0;
    while (__hip_atomic_load(gen, __ATOMIC_RELAXED, __HIP_MEMORY_SCOPE_AGENT) < target) {
      __builtin_amdgcn_s_sleep(1);
      if (++guard > (1 << 20)) break;  // failsafe: wrong answer instead of hang
    }
    asm volatile("buffer_inv sc0 sc1\n\ts_waitcnt vmcnt(0)" ::: "memory");
  }
  __syncthreads();
}

__global__ __launch_bounds__(1024, 4) void lstm_persistent(
    const unsigned short* __restrict__ xb,   // [B][T][N] bf16 (cached)
    const float* __restrict__ c_in,          // [L][B][M]
    const float* __restrict__ Wx,            // [L][4M][N]
    const float* __restrict__ Wh,            // [L][4M][M]
    const float* __restrict__ bias,          // [L][4M]
    float* __restrict__ out,                 // outs | h_last | c_last
    unsigned short* __restrict__ h0b,        // [2][B][M] bf16
    unsigned short* __restrict__ h1b,        // [2][B][M] bf16
    int* bar) {
  __shared__ short8 sW[4][32][64];  // 128 KiB fragment-packed weights
  __shared__ f32x4 red[8][64];      // 8 KiB partial-acc reduce buffer

  const int cu = blockIdx.x;
  const int tid = threadIdx.x;
  const int lane = tid & 63;
  const int wave = tid >> 6;     // 0..15
  const int khalf = wave >> 3;   // 0: kt 0..15, 1: kt 16..31
  const int wl = wave & 7;
  const int layer = wl >> 2;     // 0..1
  const int btile = wl & 3;      // 0..3
  const int q = lane >> 4;
  const int bl = lane & 15;
  const int bg = btile * 16 + bl;
  const int m0 = cu * 4;

  // ---- stage weights (once) ----
  const float* gbase[4] = { Wx, Wh, Wx + (size_t)G4M * N_SZ, Wh + (size_t)G4M * M_SZ };
  for (int mat = 0; mat < 4; ++mat) {
    const float* base = gbase[mat];
    for (int s = tid; s < 32 * 64; s += 1024) {
      int kt = s >> 6, ls = s & 63;
      int r = ls & 15;
      int k0 = kt * 32 + (ls >> 4) * 8;
      int j = (r >> 2) * 1024 + m0 + (r & 3);
      const float* src = base + (size_t)j * 1024 + k0;
      float4 a = reinterpret_cast<const float4*>(src)[0];
      float4 b2 = reinterpret_cast<const float4*>(src)[1];
      short8 w;
      w[0] = (short)f2bf(a.x); w[1] = (short)f2bf(a.y);
      w[2] = (short)f2bf(a.z); w[3] = (short)f2bf(a.w);
      w[4] = (short)f2bf(b2.x); w[5] = (short)f2bf(b2.y);
      w[6] = (short)f2bf(b2.z); w[7] = (short)f2bf(b2.w);
      sW[mat][kt][ls] = w;
    }
  }
  __syncthreads();

  // ---- per-lane state (low waves own c-state, bias, pointwise) ----
  float c_st[4] = {0.f, 0.f, 0.f, 0.f};
  float bs[4] = {0.f, 0.f, 0.f, 0.f};
  if (khalf == 0) {
#pragma unroll
    for (int e = 0; e < 4; ++e) {
      c_st[e] = c_in[layer * BM + bg * M_SZ + m0 + e];
      bs[e] = bias[layer * G4M + q * 1024 + m0 + e];
    }
  }

  const int ko = q * 8;
  const int ktb = khalf * 16;

  for (int k = 0; k <= T_STEPS; ++k) {
    const int t = layer ? (k - 1) : k;
    const bool active = layer ? (k >= 1) : (k < T_STEPS);
    f32x4 accA = { 0.f, 0.f, 0.f, 0.f };
    f32x4 accR = { 0.f, 0.f, 0.f, 0.f };
    if (active) {
      const int pr = (k + 1) & 1;  // read parity (state from iter k-1)
      if (khalf == 0) { accA[0] = bs[0]; accA[1] = bs[1]; accA[2] = bs[2]; accA[3] = bs[3]; }
      if (layer == 0) {
        const unsigned short* inA = xb + ((size_t)bg * T_STEPS + t) * N_SZ;
        const unsigned short* inR = h0b + pr * BM + bg * M_SZ;
#pragma unroll 8
        for (int kk = 0; kk < 16; ++kk) {
          int kt = ktb + kk;
          short8 fa = *reinterpret_cast<const short8*>(inA + kt * 32 + ko);
          short8 fr = *reinterpret_cast<const short8*>(inR + kt * 32 + ko);
          accA = __builtin_amdgcn_mfma_f32_16x16x32_bf16(sW[0][kt][lane], fa, accA, 0, 0, 0);
          accR = __builtin_amdgcn_mfma_f32_16x16x32_bf16(sW[1][kt][lane], fr, accR, 0, 0, 0);
        }
      } else {
        const unsigned short* inA = h0b + pr * BM + bg * M_SZ;
        const unsigned short* inR = h1b + pr * BM + bg * M_SZ;
#pragma unroll 8
        for (int kk = 0; kk < 16; ++kk) {
          int kt = ktb + kk;
          short8 fa = *reinterpret_cast<const short8*>(inA + kt * 32 + ko);
          short8 fr = *reinterpret_cast<const short8*>(inR + kt * 32 + ko);
          accA = __builtin_amdgcn_mfma_f32_16x16x32_bf16(sW[2][kt][lane], fa, accA, 0, 0, 0);
          accR = __builtin_amdgcn_mfma_f32_16x16x32_bf16(sW[3][kt][lane], fr, accR, 0, 0, 0);
        }
      }
      if (khalf == 1) red[wl][lane] = accA + accR;
    }
    __syncthreads();
    if (active && khalf == 0) {
      f32x4 tot = accA + accR + red[wl][lane];
      float hv[4];
#pragma unroll
      for (int e = 0; e < 4; ++e) {
        float ge_i = __shfl(tot[e], bl);
        float ge_f = __shfl(tot[e], bl + 16);
        float ge_g = __shfl(tot[e], bl + 32);
        float ge_o = __shfl(tot[e], bl + 48);
        float gi = sigf(ge_i);
        float gf = sigf(ge_f);
        float gg = tanhfast(ge_g);
        float go = sigf(ge_o);
        float c = gf * c_st[e] + gi * gg;
        c_st[e] = c;
        hv[e] = go * tanhfast(c);
      }
      if (q == 0) {
        const int pw = k & 1;
        unsigned short* hdst = ((layer == 0) ? h0b : h1b) + pw * BM + bg * M_SZ + m0;
        unsigned long long hb =
            (unsigned long long)f2bf(hv[0]) |
            ((unsigned long long)f2bf(hv[1]) << 16) |
            ((unsigned long long)f2bf(hv[2]) << 32) |
            ((unsigned long long)f2bf(hv[3]) << 48);
        // write-through agent store: visible at LLC once vmcnt drains
        __hip_atomic_store((unsigned long long*)hdst, hb, __ATOMIC_RELAXED,
                           __HIP_MEMORY_SCOPE_AGENT);
        if (layer == 1) {
          f32x4 ov = { hv[0], hv[1], hv[2], hv[3] };
          store_wt16(out + ((size_t)bg * T_STEPS + t) * M_SZ + m0, ov);
        }
        if (t == T_STEPS - 1) {
          f32x4 hf = { hv[0], hv[1], hv[2], hv[3] };
          f32x4 cf = { c_st[0], c_st[1], c_st[2], c_st[3] };
          store_wt16(out + OUTS + (size_t)layer * BM + (size_t)bg * M_SZ + m0, hf);
          store_wt16(out + OUTS + 2 * (size_t)BM + (size_t)layer * BM + (size_t)bg * M_SZ + m0, cf);
        }
      }
    }
    if (k < T_STEPS) grid_barrier(bar, cu, k + 1);
  }
}

extern "C" void kernel_launch(void* const* d_in, const int* in_sizes, int n_in,
                              void* d_out, int out_size, void* d_ws, size_t ws_size,
                              hipStream_t stream) {
  (void)in_sizes; (void)n_in; (void)out_size; (void)ws_size;
  const float* x  = (const float*)d_in[0];
  const float* h  = (const float*)d_in[1];
  const float* c  = (const float*)d_in[2];
  const float* Wx = (const float*)d_in[3];
  const float* Wh = (const float*)d_in[4];
  const float* b  = (const float*)d_in[5];
  float* out = (float*)d_out;

  char* ws = (char*)d_ws;
  int* bar = (int*)ws;                              // counter cachelines
  unsigned short* h0b = (unsigned short*)(ws + 4096);
  unsigned short* h1b = (unsigned short*)(ws + 4096 + 2 * BM * sizeof(unsigned short));
  unsigned short* xb  = (unsigned short*)(ws + 4096 + 4 * BM * sizeof(unsigned short));

  (void)hipMemsetAsync(ws, 0, 1024, stream);
  convert_x_kernel<<<2048, 256, 0, stream>>>(x, xb, (B_SZ * T_STEPS * N_SZ) / 4);
  init_h_kernel<<<256, 256, 0, stream>>>(h, h0b, h1b);
  lstm_persistent<<<256, 1024, 0, stream>>>(xb, c, Wx, Wh, b, out, h0b, h1b, bar);
}

// Round 5
// 4963.568 us; speedup vs baseline: 2.2769x; 1.0618x over previous
//
#include <hip/hip_runtime.h>

// LSTM stack: B=64, T=256, N=M=1024, L=2.
// Persistent cooperative kernel: 256 WGs (1/CU), 1024 threads (16 waves).
// Waves 0-7: (layer, btile) kt 0..15; waves 8-15: same (layer,btile), kt 16..31.
// Partial accs reduced via LDS. 1 relaxed tree grid-barrier per step.
// Weights bf16 fragment-packed in 128KB LDS.
// Coherence: h stores are write-through agent atomics (never dirty L2);
// out stores write-through asm (sc0 sc1); h loads are NORMAL cached loads.
// Per step, ONE leader WG per XCD (elected by CAS, XCD known via
// HW_REG_XCC_ID) issues buffer_inv sc0 sc1; everyone else does a local
// L1-only buffer_inv sc0 and waits on xgen[xcd] before loading h.

#define T_STEPS 256
#define B_SZ 64
#define M_SZ 1024
#define N_SZ 1024
#define G4M 4096
#define BM 65536                       // B*M
#define OUTS ((size_t)16777216)        // B*T*M

typedef short short8 __attribute__((ext_vector_type(8)));
typedef float f32x4 __attribute__((ext_vector_type(4)));

static __device__ __forceinline__ unsigned short f2bf(float f) {
  union { float f; unsigned int u; } v; v.f = f;
  unsigned int u = v.u;
  unsigned int r = (u + 0x7FFFu + ((u >> 16) & 1u)) >> 16;
  return (unsigned short)r;
}

static __device__ __forceinline__ float sigf(float x) {
  return 1.f / (1.f + __expf(-x));
}
static __device__ __forceinline__ float tanhfast(float x) {
  return 2.f / (1.f + __expf(-2.f * x)) - 1.f;
}

// write-through 16B store: goes to LLC, never dirties L2 (inv-safe)
static __device__ __forceinline__ void store_wt16(void* p, f32x4 v) {
  asm volatile("global_store_dwordx4 %0, %1, off sc0 sc1" :: "v"(p), "v"(v) : "memory");
}

static __device__ __forceinline__ int xcc_id() {
  int v;
  asm volatile("s_getreg_b32 %0, hwreg(HW_REG_XCC_ID)" : "=s"(v));
  return v & 7;
}

__global__ void convert_x_kernel(const float* __restrict__ x,
                                 unsigned short* __restrict__ xb, int n4) {
  int i = blockIdx.x * blockDim.x + threadIdx.x;
  int stride = gridDim.x * blockDim.x;
  for (; i < n4; i += stride) {
    float4 v = reinterpret_cast<const float4*>(x)[i];
    ushort4 o;
    o.x = f2bf(v.x); o.y = f2bf(v.y); o.z = f2bf(v.z); o.w = f2bf(v.w);
    reinterpret_cast<ushort4*>(xb)[i] = o;
  }
}

__global__ void init_h_kernel(const float* __restrict__ h,
                              unsigned short* __restrict__ h0b,
                              unsigned short* __restrict__ h1b) {
  int i = blockIdx.x * blockDim.x + threadIdx.x;  // 0..65535
  h0b[BM + i] = f2bf(h[i]);      // layer0 reads parity 1 at iter 0
  h1b[i]      = f2bf(h[BM + i]); // layer1 reads parity 0 at iter 1
}

// bar layout (64B slots): leaf[0..15]=slot 0-15, root=16, gen=17,
// claim[xcd]=18+xcd, xgen[xcd]=26+xcd.
__device__ __forceinline__ void grid_barrier_inv(int* bar, int cu, int xcd, int target) {
  __syncthreads();
  if (threadIdx.x == 0) {
    int* leaf = bar + 16 * (cu & 15);
    int* root = bar + 16 * 16;
    int* gen  = bar + 16 * 17;
    int* clx  = bar + 16 * (18 + xcd);
    int* xgen = bar + 16 * (26 + xcd);
    int prev = __hip_atomic_fetch_add(leaf, 1, __ATOMIC_RELAXED, __HIP_MEMORY_SCOPE_AGENT);
    if ((prev & 15) == 15) {                       // 16 WGs per leaf
      int pr = __hip_atomic_fetch_add(root, 1, __ATOMIC_RELAXED, __HIP_MEMORY_SCOPE_AGENT);
      if ((pr & 15) == 15) {
        __hip_atomic_fetch_add(gen, 1, __ATOMIC_RELAXED, __HIP_MEMORY_SCOPE_AGENT);
      }
    }
    int guard = 0;
    while (__hip_atomic_load(gen, __ATOMIC_RELAXED, __HIP_MEMORY_SCOPE_AGENT) < target) {
      __builtin_amdgcn_s_sleep(1);
      if (++guard > (1 << 20)) break;  // failsafe: wrong answer instead of hang
    }
    // per-XCD L2-inv leader election: exactly one winner per XCD per step
    int expected = target - 1;
    bool leader = __hip_atomic_compare_exchange_strong(
        clx, &expected, target, __ATOMIC_RELAXED, __ATOMIC_RELAXED,
        __HIP_MEMORY_SCOPE_AGENT);
    if (leader) {
      asm volatile("buffer_inv sc0 sc1\n\ts_waitcnt vmcnt(0)" ::: "memory");
      __hip_atomic_fetch_add(xgen, 1, __ATOMIC_RELAXED, __HIP_MEMORY_SCOPE_AGENT);
    } else {
      asm volatile("buffer_inv sc0\n\ts_waitcnt vmcnt(0)" ::: "memory");
      guard = 0;
      while (__hip_atomic_load(xgen, __ATOMIC_RELAXED, __HIP_MEMORY_SCOPE_AGENT) < target) {
        __builtin_amdgcn_s_sleep(1);
        if (++guard > (1 << 20)) break;
      }
    }
    asm volatile("" ::: "memory");
  }
  __syncthreads();
}

__global__ __launch_bounds__(1024, 4) void lstm_persistent(
    const unsigned short* __restrict__ xb,   // [B][T][N] bf16 (cached)
    const float* __restrict__ c_in,          // [L][B][M]
    const float* __restrict__ Wx,            // [L][4M][N]
    const float* __restrict__ Wh,            // [L][4M][M]
    const float* __restrict__ bias,          // [L][4M]
    float* __restrict__ out,                 // outs | h_last | c_last
    unsigned short* __restrict__ h0b,        // [2][B][M] bf16
    unsigned short* __restrict__ h1b,        // [2][B][M] bf16
    int* bar) {
  __shared__ short8 sW[4][32][64];  // 128 KiB fragment-packed weights
  __shared__ f32x4 red[8][64];      // 8 KiB partial-acc reduce buffer

  const int cu = blockIdx.x;
  const int tid = threadIdx.x;
  const int lane = tid & 63;
  const int wave = tid >> 6;     // 0..15
  const int khalf = wave >> 3;   // 0: kt 0..15, 1: kt 16..31
  const int wl = wave & 7;
  const int layer = wl >> 2;     // 0..1
  const int btile = wl & 3;      // 0..3
  const int q = lane >> 4;
  const int bl = lane & 15;
  const int bg = btile * 16 + bl;
  const int m0 = cu * 4;
  const int xcd = xcc_id();

  // ---- stage weights (once) ----
  const float* gbase[4] = { Wx, Wh, Wx + (size_t)G4M * N_SZ, Wh + (size_t)G4M * M_SZ };
  for (int mat = 0; mat < 4; ++mat) {
    const float* base = gbase[mat];
    for (int s = tid; s < 32 * 64; s += 1024) {
      int kt = s >> 6, ls = s & 63;
      int r = ls & 15;
      int k0 = kt * 32 + (ls >> 4) * 8;
      int j = (r >> 2) * 1024 + m0 + (r & 3);
      const float* src = base + (size_t)j * 1024 + k0;
      float4 a = reinterpret_cast<const float4*>(src)[0];
      float4 b2 = reinterpret_cast<const float4*>(src)[1];
      short8 w;
      w[0] = (short)f2bf(a.x); w[1] = (short)f2bf(a.y);
      w[2] = (short)f2bf(a.z); w[3] = (short)f2bf(a.w);
      w[4] = (short)f2bf(b2.x); w[5] = (short)f2bf(b2.y);
      w[6] = (short)f2bf(b2.z); w[7] = (short)f2bf(b2.w);
      sW[mat][kt][ls] = w;
    }
  }
  __syncthreads();

  // ---- per-lane state (low waves own c-state, bias, pointwise) ----
  float c_st[4] = {0.f, 0.f, 0.f, 0.f};
  float bs[4] = {0.f, 0.f, 0.f, 0.f};
  if (khalf == 0) {
#pragma unroll
    for (int e = 0; e < 4; ++e) {
      c_st[e] = c_in[layer * BM + bg * M_SZ + m0 + e];
      bs[e] = bias[layer * G4M + q * 1024 + m0 + e];
    }
  }

  const int ko = q * 8;
  const int ktb = khalf * 16;

  // x prefetch registers (layer-0 waves): first 8 of this wave's 16 kt
  short8 xpre[8];
  if (layer == 0) {
    const unsigned short* inN = xb + ((size_t)bg * T_STEPS + 0) * N_SZ;
#pragma unroll
    for (int kk = 0; kk < 8; ++kk)
      xpre[kk] = *reinterpret_cast<const short8*>(inN + (ktb + kk) * 32 + ko);
  }

  for (int k = 0; k <= T_STEPS; ++k) {
    const int t = layer ? (k - 1) : k;
    const bool active = layer ? (k >= 1) : (k < T_STEPS);
    f32x4 accA = { 0.f, 0.f, 0.f, 0.f };
    f32x4 accR = { 0.f, 0.f, 0.f, 0.f };
    if (active) {
      const int pr = (k + 1) & 1;  // read parity (state from iter k-1)
      if (khalf == 0) { accA[0] = bs[0]; accA[1] = bs[1]; accA[2] = bs[2]; accA[3] = bs[3]; }
      if (layer == 0) {
        const unsigned short* inA = xb + ((size_t)bg * T_STEPS + t) * N_SZ;
        const unsigned short* inR = h0b + pr * BM + bg * M_SZ;
#pragma unroll
        for (int kk = 0; kk < 16; ++kk) {
          int kt = ktb + kk;
          short8 fa = (kk < 8) ? xpre[kk]
                    : *reinterpret_cast<const short8*>(inA + kt * 32 + ko);
          short8 fr = *reinterpret_cast<const short8*>(inR + kt * 32 + ko);
          accA = __builtin_amdgcn_mfma_f32_16x16x32_bf16(sW[0][kt][lane], fa, accA, 0, 0, 0);
          accR = __builtin_amdgcn_mfma_f32_16x16x32_bf16(sW[1][kt][lane], fr, accR, 0, 0, 0);
        }
      } else {
        const unsigned short* inA = h0b + pr * BM + bg * M_SZ;
        const unsigned short* inR = h1b + pr * BM + bg * M_SZ;
#pragma unroll
        for (int kk = 0; kk < 16; ++kk) {
          int kt = ktb + kk;
          short8 fa = *reinterpret_cast<const short8*>(inA + kt * 32 + ko);
          short8 fr = *reinterpret_cast<const short8*>(inR + kt * 32 + ko);
          accA = __builtin_amdgcn_mfma_f32_16x16x32_bf16(sW[2][kt][lane], fa, accA, 0, 0, 0);
          accR = __builtin_amdgcn_mfma_f32_16x16x32_bf16(sW[3][kt][lane], fr, accR, 0, 0, 0);
        }
      }
      if (khalf == 1) red[wl][lane] = accA + accR;
    }
    __syncthreads();
    if (active && khalf == 0) {
      f32x4 tot = accA + accR + red[wl][lane];
      float hv[4];
#pragma unroll
      for (int e = 0; e < 4; ++e) {
        float ge_i = __shfl(tot[e], bl);
        float ge_f = __shfl(tot[e], bl + 16);
        float ge_g = __shfl(tot[e], bl + 32);
        float ge_o = __shfl(tot[e], bl + 48);
        float gi = sigf(ge_i);
        float gf = sigf(ge_f);
        float gg = tanhfast(ge_g);
        float go = sigf(ge_o);
        float c = gf * c_st[e] + gi * gg;
        c_st[e] = c;
        hv[e] = go * tanhfast(c);
      }
      if (q == 0) {
        const int pw = k & 1;
        unsigned short* hdst = ((layer == 0) ? h0b : h1b) + pw * BM + bg * M_SZ + m0;
        unsigned long long hb =
            (unsigned long long)f2bf(hv[0]) |
            ((unsigned long long)f2bf(hv[1]) << 16) |
            ((unsigned long long)f2bf(hv[2]) << 32) |
            ((unsigned long long)f2bf(hv[3]) << 48);
        // write-through agent store: visible at LLC once vmcnt drains
        __hip_atomic_store((unsigned long long*)hdst, hb, __ATOMIC_RELAXED,
                           __HIP_MEMORY_SCOPE_AGENT);
        if (layer == 1) {
          f32x4 ov = { hv[0], hv[1], hv[2], hv[3] };
          store_wt16(out + ((size_t)bg * T_STEPS + t) * M_SZ + m0, ov);
        }
        if (t == T_STEPS - 1) {
          f32x4 hf = { hv[0], hv[1], hv[2], hv[3] };
          f32x4 cf = { c_st[0], c_st[1], c_st[2], c_st[3] };
          store_wt16(out + OUTS + (size_t)layer * BM + (size_t)bg * M_SZ + m0, hf);
          store_wt16(out + OUTS + 2 * (size_t)BM + (size_t)layer * BM + (size_t)bg * M_SZ + m0, cf);
        }
      }
    }
    // prefetch next step's x fragments (read-only, no sync needed)
    if (layer == 0 && k + 1 < T_STEPS) {
      const unsigned short* inN = xb + ((size_t)bg * T_STEPS + (k + 1)) * N_SZ;
#pragma unroll
      for (int kk = 0; kk < 8; ++kk)
        xpre[kk] = *reinterpret_cast<const short8*>(inN + (ktb + kk) * 32 + ko);
    }
    if (k < T_STEPS) grid_barrier_inv(bar, cu, xcd, k + 1);
  }
}

extern "C" void kernel_launch(void* const* d_in, const int* in_sizes, int n_in,
                              void* d_out, int out_size, void* d_ws, size_t ws_size,
                              hipStream_t stream) {
  (void)in_sizes; (void)n_in; (void)out_size; (void)ws_size;
  const float* x  = (const float*)d_in[0];
  const float* h  = (const float*)d_in[1];
  const float* c  = (const float*)d_in[2];
  const float* Wx = (const float*)d_in[3];
  const float* Wh = (const float*)d_in[4];
  const float* b  = (const float*)d_in[5];
  float* out = (float*)d_out;

  char* ws = (char*)d_ws;
  int* bar = (int*)ws;                              // counter cachelines
  unsigned short* h0b = (unsigned short*)(ws + 4096);
  unsigned short* h1b = (unsigned short*)(ws + 4096 + 2 * BM * sizeof(unsigned short));
  unsigned short* xb  = (unsigned short*)(ws + 4096 + 4 * BM * sizeof(unsigned short));

  (void)hipMemsetAsync(ws, 0, 4096, stream);
  convert_x_kernel<<<2048, 256, 0, stream>>>(x, xb, (B_SZ * T_STEPS * N_SZ) / 4);
  init_h_kernel<<<256, 256, 0, stream>>>(h, h0b, h1b);
  lstm_persistent<<<256, 1024, 0, stream>>>(xb, c, Wx, Wh, b, out, h0b, h1b, bar);
}

// Round 6
// 3957.290 us; speedup vs baseline: 2.8559x; 1.2543x over previous
//
#include <hip/hip_runtime.h>

// LSTM stack: B=64, T=256, N=M=1024, L=2.
// Persistent cooperative kernel: 256 WGs (1/CU), 1024 threads (16 waves).
// Mat-paired wave groups (dedup h0 reads):
//   group A (waves 0-7,  bt=w&3, kh=(w>>2)&1): reads h0 once -> MFMA Wh0 (l0) + Wx1 (l1)
//   group B (waves 8-15, bt=w&3, kh=(w>>2)&1): reads x, h1   -> MFMA Wx0 (l0) + Wh1 (l1)
// Deep explicit load pipeline (A: 16 frags preloaded; B: 4-chunk ring).
// Partials reduced via red1/red2 LDS. Weights bf16 fragment-packed in 128KB LDS.
// Coherence: h stores write-through agent atomics; per step ONE static leader WG
// per XCD (CAS-elected once) invs L2 (sc0 sc1), others inv L1 only and poll
// their per-XCD xgen line (8 pollers on gen, 31 per xgen line).

#define T_STEPS 256
#define B_SZ 64
#define M_SZ 1024
#define N_SZ 1024
#define G4M 4096
#define BM 65536                       // B*M
#define OUTS ((size_t)16777216)        // B*T*M

typedef short short8 __attribute__((ext_vector_type(8)));
typedef float f32x4 __attribute__((ext_vector_type(4)));

static __device__ __forceinline__ unsigned short f2bf(float f) {
  union { float f; unsigned int u; } v; v.f = f;
  unsigned int u = v.u;
  unsigned int r = (u + 0x7FFFu + ((u >> 16) & 1u)) >> 16;
  return (unsigned short)r;
}

static __device__ __forceinline__ float sigf(float x) {
  return 1.f / (1.f + __expf(-x));
}
static __device__ __forceinline__ float tanhfast(float x) {
  return 2.f / (1.f + __expf(-2.f * x)) - 1.f;
}

static __device__ __forceinline__ short8 ld16(const unsigned short* p) {
  return *reinterpret_cast<const short8*>(p);
}

// write-through 16B store: goes to LLC, never dirties L2 (inv-safe)
static __device__ __forceinline__ void store_wt16(void* p, f32x4 v) {
  asm volatile("global_store_dwordx4 %0, %1, off sc0 sc1" :: "v"(p), "v"(v) : "memory");
}

static __device__ __forceinline__ int xcc_id() {
  int v;
  asm volatile("s_getreg_b32 %0, hwreg(HW_REG_XCC_ID)" : "=s"(v));
  return v & 7;
}

__global__ void convert_x_kernel(const float* __restrict__ x,
                                 unsigned short* __restrict__ xb, int n4) {
  int i = blockIdx.x * blockDim.x + threadIdx.x;
  int stride = gridDim.x * blockDim.x;
  for (; i < n4; i += stride) {
    float4 v = reinterpret_cast<const float4*>(x)[i];
    ushort4 o;
    o.x = f2bf(v.x); o.y = f2bf(v.y); o.z = f2bf(v.z); o.w = f2bf(v.w);
    reinterpret_cast<ushort4*>(xb)[i] = o;
  }
}

__global__ void init_h_kernel(const float* __restrict__ h,
                              unsigned short* __restrict__ h0b,
                              unsigned short* __restrict__ h1b) {
  int i = blockIdx.x * blockDim.x + threadIdx.x;  // 0..65535
  h0b[BM + i] = f2bf(h[i]);      // layer0 reads parity 1 at iter 0
  h1b[i]      = f2bf(h[BM + i]); // layer1 reads parity 0 at iter 1
}

// bar slots (64B each): leaf[0..15]=0-15, root=16, gen=17, lead[xcd]=18+x, xgen[xcd]=26+x
__device__ __forceinline__ void grid_barrier_inv(int* bar, int cu, int xcd,
                                                 bool leader, int target) {
  __syncthreads();
  if (threadIdx.x == 0) {
    int* leaf = bar + 16 * (cu & 15);
    int* root = bar + 16 * 16;
    int* gen  = bar + 16 * 17;
    int* xgen = bar + 16 * (26 + xcd);
    int prev = __hip_atomic_fetch_add(leaf, 1, __ATOMIC_RELAXED, __HIP_MEMORY_SCOPE_AGENT);
    if ((prev & 15) == 15) {                       // 16 WGs per leaf
      int pr2 = __hip_atomic_fetch_add(root, 1, __ATOMIC_RELAXED, __HIP_MEMORY_SCOPE_AGENT);
      if ((pr2 & 15) == 15) {
        __hip_atomic_fetch_add(gen, 1, __ATOMIC_RELAXED, __HIP_MEMORY_SCOPE_AGENT);
      }
    }
    int guard = 0;
    if (leader) {
      while (__hip_atomic_load(gen, __ATOMIC_RELAXED, __HIP_MEMORY_SCOPE_AGENT) < target) {
        __builtin_amdgcn_s_sleep(1);
        if (++guard > (1 << 20)) break;  // failsafe: wrong answer instead of hang
      }
      asm volatile("buffer_inv sc0 sc1\n\ts_waitcnt vmcnt(0)" ::: "memory");
      __hip_atomic_fetch_add(xgen, 1, __ATOMIC_RELAXED, __HIP_MEMORY_SCOPE_AGENT);
    } else {
      while (__hip_atomic_load(xgen, __ATOMIC_RELAXED, __HIP_MEMORY_SCOPE_AGENT) < target) {
        __builtin_amdgcn_s_sleep(1);
        if (++guard > (1 << 20)) break;
      }
      asm volatile("buffer_inv sc0\n\ts_waitcnt vmcnt(0)" ::: "memory");
    }
  }
  __syncthreads();
}

__global__ __launch_bounds__(1024, 4) void lstm_persistent(
    const unsigned short* __restrict__ xb,   // [B][T][N] bf16 (cached)
    const float* __restrict__ c_in,          // [L][B][M]
    const float* __restrict__ Wx,            // [L][4M][N]
    const float* __restrict__ Wh,            // [L][4M][M]
    const float* __restrict__ bias,          // [L][4M]
    float* __restrict__ out,                 // outs | h_last | c_last
    unsigned short* __restrict__ h0b,        // [2][B][M] bf16
    unsigned short* __restrict__ h1b,        // [2][B][M] bf16
    int* bar) {
  __shared__ short8 sW[4][32][64];   // 128 KiB fragment-packed weights
  __shared__ f32x4 red1[12][64];     // 12 KiB l0 partials
  __shared__ f32x4 red2[12][64];     // 12 KiB l1 partials

  const int cu = blockIdx.x;
  const int tid = threadIdx.x;
  const int lane = tid & 63;
  const int w = tid >> 6;        // 0..15
  const bool grpA = (w < 8);
  const int kh = (w >> 2) & 1;   // k-half
  const int bt = w & 3;          // batch tile
  const int q = lane >> 4;
  const int bl = lane & 15;
  const int bg = bt * 16 + bl;
  const int m0 = cu * 4;
  const int xcd = xcc_id();

  // ---- stage weights (once) ----
  const float* gbase[4] = { Wx, Wh, Wx + (size_t)G4M * N_SZ, Wh + (size_t)G4M * M_SZ };
  for (int mat = 0; mat < 4; ++mat) {
    const float* base = gbase[mat];
    for (int s = tid; s < 32 * 64; s += 1024) {
      int kt = s >> 6, ls = s & 63;
      int r = ls & 15;
      int k0 = kt * 32 + (ls >> 4) * 8;
      int j = (r >> 2) * 1024 + m0 + (r & 3);
      const float* src = base + (size_t)j * 1024 + k0;
      float4 a = reinterpret_cast<const float4*>(src)[0];
      float4 b2 = reinterpret_cast<const float4*>(src)[1];
      short8 wv;
      wv[0] = (short)f2bf(a.x); wv[1] = (short)f2bf(a.y);
      wv[2] = (short)f2bf(a.z); wv[3] = (short)f2bf(a.w);
      wv[4] = (short)f2bf(b2.x); wv[5] = (short)f2bf(b2.y);
      wv[6] = (short)f2bf(b2.z); wv[7] = (short)f2bf(b2.w);
      sW[mat][kt][ls] = wv;
    }
  }

  // ---- static per-XCD leader election (once) ----
  bool leader = false;
  if (tid == 0) {
    int expected = 0;
    leader = __hip_atomic_compare_exchange_strong(
        bar + 16 * (18 + xcd), &expected, cu + 1, __ATOMIC_RELAXED,
        __ATOMIC_RELAXED, __HIP_MEMORY_SCOPE_AGENT);
  }
  __syncthreads();

  // ---- pointwise-owner state ----
  // l0 owner: waves 0..3 (A, kh=0). l1 owner: waves 8..11 (B, kh=0).
  float c_st[4] = {0.f, 0.f, 0.f, 0.f};
  float bs[4] = {0.f, 0.f, 0.f, 0.f};
  if (kh == 0) {
    const int layer = grpA ? 0 : 1;
#pragma unroll
    for (int e = 0; e < 4; ++e) {
      c_st[e] = c_in[layer * BM + bg * M_SZ + m0 + e];
      bs[e] = bias[layer * G4M + q * 1024 + m0 + e];
    }
  }

  const int ko = q * 8;
  const int ktb = kh * 16;

  // B waves: x chunk-0 prefetch (x is read-only; stale caches are fine)
  short8 pfx[4];
  if (!grpA) {
    const unsigned short* px = xb + ((size_t)bg * T_STEPS + 0) * N_SZ;
#pragma unroll
    for (int j = 0; j < 4; ++j) pfx[j] = ld16(px + (ktb + j) * 32 + ko);
  }

  for (int k = 0; k <= T_STEPS; ++k) {
    const int pr = (k + 1) & 1;  // read parity (state produced at iter k-1)
    f32x4 acc0 = { 0.f, 0.f, 0.f, 0.f };   // l0-product partial
    f32x4 acc1 = { 0.f, 0.f, 0.f, 0.f };   // l1-product partial
    if (kh == 0) {
      if (grpA) { acc0[0] = bs[0]; acc0[1] = bs[1]; acc0[2] = bs[2]; acc0[3] = bs[3]; }
      else      { acc1[0] = bs[0]; acc1[1] = bs[1]; acc1[2] = bs[2]; acc1[3] = bs[3]; }
    }

    if (grpA) {
      // ---- group A: read h0 once; MFMA Wh0 (->acc0) and Wx1 (->acc1) ----
      const unsigned short* ph0 = h0b + pr * BM + (size_t)bg * M_SZ;
      short8 a0[8], a1[8];
#pragma unroll
      for (int j = 0; j < 8; ++j) a0[j] = ld16(ph0 + (ktb + j) * 32 + ko);
#pragma unroll
      for (int j = 0; j < 8; ++j) a1[j] = ld16(ph0 + (ktb + 8 + j) * 32 + ko);
#pragma unroll
      for (int j = 0; j < 8; ++j) {
        int kt = ktb + j;
        acc0 = __builtin_amdgcn_mfma_f32_16x16x32_bf16(sW[1][kt][lane], a0[j], acc0, 0, 0, 0);
        acc1 = __builtin_amdgcn_mfma_f32_16x16x32_bf16(sW[2][kt][lane], a0[j], acc1, 0, 0, 0);
      }
#pragma unroll
      for (int j = 0; j < 8; ++j) {
        int kt = ktb + 8 + j;
        acc0 = __builtin_amdgcn_mfma_f32_16x16x32_bf16(sW[1][kt][lane], a1[j], acc0, 0, 0, 0);
        acc1 = __builtin_amdgcn_mfma_f32_16x16x32_bf16(sW[2][kt][lane], a1[j], acc1, 0, 0, 0);
      }
    } else {
      // ---- group B: read x + h1; MFMA Wx0 (->acc0) and Wh1 (->acc1) ----
      const int tl0 = (k < T_STEPS) ? k : (T_STEPS - 1);
      const unsigned short* px = xb + ((size_t)bg * T_STEPS + tl0) * N_SZ;
      const unsigned short* ph1 = h1b + pr * BM + (size_t)bg * M_SZ;
      short8 bx[2][4], bh[2][4];
#pragma unroll
      for (int j = 0; j < 4; ++j) {
        bx[0][j] = pfx[j];
        bh[0][j] = ld16(ph1 + (ktb + j) * 32 + ko);
      }
#pragma unroll
      for (int c = 0; c < 4; ++c) {
        const int cur = c & 1, nxt = cur ^ 1;
        if (c < 3) {
#pragma unroll
          for (int j = 0; j < 4; ++j) {
            int kt = ktb + (c + 1) * 4 + j;
            bx[nxt][j] = ld16(px + kt * 32 + ko);
            bh[nxt][j] = ld16(ph1 + kt * 32 + ko);
          }
        }
#pragma unroll
        for (int j = 0; j < 4; ++j) {
          int kt = ktb + c * 4 + j;
          acc0 = __builtin_amdgcn_mfma_f32_16x16x32_bf16(sW[0][kt][lane], bx[cur][j], acc0, 0, 0, 0);
          acc1 = __builtin_amdgcn_mfma_f32_16x16x32_bf16(sW[3][kt][lane], bh[cur][j], acc1, 0, 0, 0);
        }
      }
    }

    // ---- partial-sum exchange ----
    if (w >= 4 && w < 8)       { red1[bt][lane] = acc0; red2[4 + bt][lane] = acc1; }
    else if (w < 4)            { red2[bt][lane] = acc1; }
    else if (w >= 12)          { red1[8 + bt][lane] = acc0; red2[8 + bt][lane] = acc1; }
    else /* 8..11 */           { red1[4 + bt][lane] = acc0; }
    __syncthreads();

    // ---- layer-0 pointwise (waves 0..3), t = k ----
    if (w < 4 && k < T_STEPS) {
      f32x4 tot = acc0 + red1[bt][lane] + red1[4 + bt][lane] + red1[8 + bt][lane];
      float hv[4];
#pragma unroll
      for (int e = 0; e < 4; ++e) {
        float ge_i = __shfl(tot[e], bl);
        float ge_f = __shfl(tot[e], bl + 16);
        float ge_g = __shfl(tot[e], bl + 32);
        float ge_o = __shfl(tot[e], bl + 48);
        float gi = sigf(ge_i), gf = sigf(ge_f);
        float gg = tanhfast(ge_g), go = sigf(ge_o);
        float c = gf * c_st[e] + gi * gg;
        c_st[e] = c;
        hv[e] = go * tanhfast(c);
      }
      if (q == 0) {
        unsigned short* hdst = h0b + (k & 1) * BM + (size_t)bg * M_SZ + m0;
        unsigned long long hb =
            (unsigned long long)f2bf(hv[0]) |
            ((unsigned long long)f2bf(hv[1]) << 16) |
            ((unsigned long long)f2bf(hv[2]) << 32) |
            ((unsigned long long)f2bf(hv[3]) << 48);
        __hip_atomic_store((unsigned long long*)hdst, hb, __ATOMIC_RELAXED,
                           __HIP_MEMORY_SCOPE_AGENT);
        if (k == T_STEPS - 1) {
          f32x4 hf = { hv[0], hv[1], hv[2], hv[3] };
          f32x4 cf = { c_st[0], c_st[1], c_st[2], c_st[3] };
          store_wt16(out + OUTS + (size_t)bg * M_SZ + m0, hf);
          store_wt16(out + OUTS + 2 * (size_t)BM + (size_t)bg * M_SZ + m0, cf);
        }
      }
    }

    // ---- layer-1 pointwise (waves 8..11), t = k-1 ----
    if (w >= 8 && w < 12 && k >= 1) {
      const int t = k - 1;
      f32x4 tot = acc1 + red2[bt][lane] + red2[4 + bt][lane] + red2[8 + bt][lane];
      float hv[4];
#pragma unroll
      for (int e = 0; e < 4; ++e) {
        float ge_i = __shfl(tot[e], bl);
        float ge_f = __shfl(tot[e], bl + 16);
        float ge_g = __shfl(tot[e], bl + 32);
        float ge_o = __shfl(tot[e], bl + 48);
        float gi = sigf(ge_i), gf = sigf(ge_f);
        float gg = tanhfast(ge_g), go = sigf(ge_o);
        float c = gf * c_st[e] + gi * gg;
        c_st[e] = c;
        hv[e] = go * tanhfast(c);
      }
      if (q == 0) {
        unsigned short* hdst = h1b + (k & 1) * BM + (size_t)bg * M_SZ + m0;
        unsigned long long hb =
            (unsigned long long)f2bf(hv[0]) |
            ((unsigned long long)f2bf(hv[1]) << 16) |
            ((unsigned long long)f2bf(hv[2]) << 32) |
            ((unsigned long long)f2bf(hv[3]) << 48);
        __hip_atomic_store((unsigned long long*)hdst, hb, __ATOMIC_RELAXED,
                           __HIP_MEMORY_SCOPE_AGENT);
        f32x4 ov = { hv[0], hv[1], hv[2], hv[3] };
        store_wt16(out + ((size_t)bg * T_STEPS + t) * M_SZ + m0, ov);
        if (k == T_STEPS) {
          f32x4 hf = { hv[0], hv[1], hv[2], hv[3] };
          f32x4 cf = { c_st[0], c_st[1], c_st[2], c_st[3] };
          store_wt16(out + OUTS + (size_t)BM + (size_t)bg * M_SZ + m0, hf);
          store_wt16(out + OUTS + 3 * (size_t)BM + (size_t)bg * M_SZ + m0, cf);
        }
      }
    }

    // B waves: prefetch next step's x chunk-0 (no sync needed)
    if (!grpA && k < T_STEPS) {
      const int tn = (k + 1 < T_STEPS) ? (k + 1) : (T_STEPS - 1);
      const unsigned short* px = xb + ((size_t)bg * T_STEPS + tn) * N_SZ;
#pragma unroll
      for (int j = 0; j < 4; ++j) pfx[j] = ld16(px + (ktb + j) * 32 + ko);
    }

    if (k < T_STEPS) grid_barrier_inv(bar, cu, xcd, leader, k + 1);
  }
}

extern "C" void kernel_launch(void* const* d_in, const int* in_sizes, int n_in,
                              void* d_out, int out_size, void* d_ws, size_t ws_size,
                              hipStream_t stream) {
  (void)in_sizes; (void)n_in; (void)out_size; (void)ws_size;
  const float* x  = (const float*)d_in[0];
  const float* h  = (const float*)d_in[1];
  const float* c  = (const float*)d_in[2];
  const float* Wx = (const float*)d_in[3];
  const float* Wh = (const float*)d_in[4];
  const float* b  = (const float*)d_in[5];
  float* out = (float*)d_out;

  char* ws = (char*)d_ws;
  int* bar = (int*)ws;                              // counter cachelines
  unsigned short* h0b = (unsigned short*)(ws + 4096);
  unsigned short* h1b = (unsigned short*)(ws + 4096 + 2 * BM * sizeof(unsigned short));
  unsigned short* xb  = (unsigned short*)(ws + 4096 + 4 * BM * sizeof(unsigned short));

  (void)hipMemsetAsync(ws, 0, 4096, stream);
  convert_x_kernel<<<2048, 256, 0, stream>>>(x, xb, (B_SZ * T_STEPS * N_SZ) / 4);
  init_h_kernel<<<256, 256, 0, stream>>>(h, h0b, h1b);
  lstm_persistent<<<256, 1024, 0, stream>>>(xb, c, Wx, Wh, b, out, h0b, h1b, bar);
}